// Round 7
// baseline (94.904 us; speedup 1.0000x reference)
//
#include <hip/hip_runtime.h>
#include <hip/hip_fp16.h>
#include <math.h>

#define NB    (1 << 20)
#define HH    512
#define WW    1024
#define RANK  16
#define FC    128
#define HW    (HH * WW)
#define TPB   256

typedef float        f32x16 __attribute__((ext_vector_type(16)));
typedef _Float16     f16x8  __attribute__((ext_vector_type(8)));
typedef _Float16     h2     __attribute__((ext_vector_type(2)));
typedef unsigned int uint2v __attribute__((ext_vector_type(2)));

// cvt_pkrtz returns __fp16x2; bit-identical re-type to our h2 (_Float16x2)
__device__ __forceinline__ h2 pkrtz(float a, float b) {
    return __builtin_bit_cast(h2, __builtin_amdgcn_cvt_pkrtz(a, b));
}

// ---------------------------------------------------------------------------
// Pre-pass: planar bg_mat [16][H][W] fp32 -> interleaved f16 tex [H*W][16]
// (one bilinear tap = one 32B half-line)
// ---------------------------------------------------------------------------
__global__ __launch_bounds__(256) void transpose_f16_kernel(
    const float* __restrict__ bg, __half* __restrict__ tex)
{
    const int t = blockIdx.x * 256 + threadIdx.x;
    union { unsigned short s[16]; uint4 q[2]; } pk;
    #pragma unroll
    for (int c = 0; c < RANK; ++c) {
        __half h = __float2half_rn(bg[c * HW + t]);
        pk.s[c] = *reinterpret_cast<unsigned short*>(&h);
    }
    uint4* dst = (uint4*)(tex + (size_t)t * 16);
    dst[0] = pk.q[0];
    dst[1] = pk.q[1];
}

// ---------------------------------------------------------------------------
// Fused render, all-f16 datapath, 1 sample/thread, barrier-free:
// gather(f16 tex) -> pk_fma blend (result IS the MFMA B-fragment)
// -> permlane32_swap wave transpose -> GEMM1 16->128 (f16 MFMA) -> relu +
// cvt_pkrtz -> GEMM2 128->3 (f16 MFMA, K-permuted so GEMM1 C-layout ==
// GEMM2 B-layout). MODE 0: f16 tex; MODE 1: planar f32 fallback.
// ---------------------------------------------------------------------------
template <int MODE>
__global__ __launch_bounds__(TPB, 3) void bg_render_mfma(
    const float* __restrict__ viewdirs,
    const void*  __restrict__ srcv,
    const float* __restrict__ W1,      // [16][128] row-major
    const float* __restrict__ W2,      // [128][3] row-major
    float* __restrict__ out)
{
    const int tid = threadIdx.x;
    const int l31 = tid & 31;
    const int q5  = (tid >> 5) & 1;

    const f32x16 kZero = {0.f,0.f,0.f,0.f,0.f,0.f,0.f,0.f,
                          0.f,0.f,0.f,0.f,0.f,0.f,0.f,0.f};

    // ---- GEMM1 A-fragments: A[row=j_local][k] = W1[k][32*jt + j_local] ----
    f16x8 w1f[4];
    #pragma unroll
    for (int jt = 0; jt < 4; ++jt) {
        f16x8 v;
        #pragma unroll
        for (int ii = 0; ii < 8; ++ii)
            v[ii] = (_Float16)W1[(8 * q5 + ii) * FC + 32 * jt + l31];
        w1f[jt] = v;
    }

    // ---- GEMM2 A-fragments, K-permuted: neuron n = 16*kt+8*(i>>2)+4*q5+(i&3)
    // rows 0-2 = W2 cols; rows 4-6 duplicate them so both lane-halves see all 3.
    f16x8 w2f[8];
    {
        const bool ok = ((l31 & 3) < 3) && (l31 < 8);
        const int  c3 = l31 & 3;
        #pragma unroll
        for (int kt = 0; kt < 8; ++kt) {
            f16x8 v;
            #pragma unroll
            for (int ii = 0; ii < 8; ++ii) {
                const int n = 16 * kt + 8 * (ii >> 2) + 4 * q5 + (ii & 3);
                v[ii] = ok ? (_Float16)W2[3 * n + c3] : (_Float16)0.0f;
            }
            w2f[kt] = v;
        }
    }

    const int i = blockIdx.x * TPB + tid;   // this thread's sample

    // ---- equirect unwrap + bilinear setup (identical math to reference) ----
    const float dx = viewdirs[3 * i + 0];
    const float dy = viewdirs[3 * i + 1];
    const float dz = viewdirs[3 * i + 2];
    const float INV_PI = 0.31830988618379067154f;
    float phi   = atan2f(dy, dx);
    float theta = acosf(fminf(fmaxf(dz, -1.0f), 1.0f));
    float gx = phi * INV_PI;
    float gy = theta * (2.0f * INV_PI) - 1.0f;

    float ix = (gx + 1.0f) * (0.5f * (float)WW) - 0.5f;
    float iy = (gy + 1.0f) * (0.5f * (float)HH) - 0.5f;
    float x0f = floorf(ix), y0f = floorf(iy);
    float wx1 = ix - x0f, wx0 = 1.0f - wx1;
    float wy1 = iy - y0f, wy0 = 1.0f - wy1;
    int x0 = (int)x0f, y0 = (int)y0f;
    int x1 = x0 + 1,   y1 = y0 + 1;

    float w00 = wx0 * wy0, w10 = wx1 * wy0, w01 = wx0 * wy1, w11 = wx1 * wy1;
    bool vx0 = (x0 >= 0) & (x0 <= WW - 1);
    bool vx1 = (x1 >= 0) & (x1 <= WW - 1);
    bool vy0 = (y0 >= 0) & (y0 <= HH - 1);
    bool vy1 = (y1 >= 0) & (y1 <= HH - 1);
    if (!(vx0 & vy0)) w00 = 0.0f;
    if (!(vx1 & vy0)) w10 = 0.0f;
    if (!(vx0 & vy1)) w01 = 0.0f;
    if (!(vx1 & vy1)) w11 = 0.0f;

    int cx0 = min(max(x0, 0), WW - 1), cx1 = min(max(x1, 0), WW - 1);
    int cy0 = min(max(y0, 0), HH - 1), cy1 = min(max(y1, 0), HH - 1);
    int b00 = cy0 * WW + cx0, b10 = cy0 * WW + cx1;
    int b01 = cy1 * WW + cx0, b11 = cy1 * WW + cx1;

    // ---- gather + blend: e[8] (h2) = this sample's 16-ch emb in f16 ----
    h2 e[8];
    if (MODE == 0) {
        const __half* tex = (const __half*)srcv;
        union Tap { uint4 q[2]; h2 h[8]; } t00, t10, t01, t11;
        const uint4* p;
        p = (const uint4*)(tex + (size_t)b00 * 16); t00.q[0] = p[0]; t00.q[1] = p[1];
        p = (const uint4*)(tex + (size_t)b10 * 16); t10.q[0] = p[0]; t10.q[1] = p[1];
        p = (const uint4*)(tex + (size_t)b01 * 16); t01.q[0] = p[0]; t01.q[1] = p[1];
        p = (const uint4*)(tex + (size_t)b11 * 16); t11.q[0] = p[0]; t11.q[1] = p[1];

        h2 W00, W10, W01, W11;
        W00[0] = W00[1] = (_Float16)w00;
        W10[0] = W10[1] = (_Float16)w10;
        W01[0] = W01[1] = (_Float16)w01;
        W11[0] = W11[1] = (_Float16)w11;
        #pragma unroll
        for (int d = 0; d < 8; ++d)
            e[d] = t00.h[d] * W00 + t10.h[d] * W10 + t01.h[d] * W01 + t11.h[d] * W11;
    } else {
        const float* src = (const float*)srcv;
        float ef[RANK];
        #pragma unroll
        for (int ch = 0; ch < RANK; ++ch) {
            const float* img = src + ch * HW;
            ef[ch] = img[b00] * w00 + img[b10] * w10
                   + img[b01] * w01 + img[b11] * w11;
        }
        #pragma unroll
        for (int d = 0; d < 8; ++d)
            e[d] = pkrtz(ef[2 * d], ef[2 * d + 1]);
    }

    // ---- wave transpose: 4 permlane32_swap build BOTH groups' B-frags ----
    union FragU { f16x8 v; h2 h[4]; unsigned int u[4]; };
    FragU bq0, bq1;
    #pragma unroll
    for (int d = 0; d < 4; ++d) {
        unsigned int lo = __builtin_bit_cast(unsigned int, e[d]);
        unsigned int hi = __builtin_bit_cast(unsigned int, e[d + 4]);
        uint2v r = __builtin_amdgcn_permlane32_swap(lo, hi, false, false);
        bq0.u[d] = r.x;
        bq1.u[d] = r.y;
    }

    // ---- MFMA pipeline: 4 jt x (2 GEMM1 + 4 GEMM2), all f16 ----
    f32x16 accA = kZero, accB = kZero;
    #pragma unroll
    for (int jt = 0; jt < 4; ++jt) {
        f32x16 h0 = __builtin_amdgcn_mfma_f32_32x32x16_f16(w1f[jt], bq0.v, kZero, 0, 0, 0);
        f32x16 h1 = __builtin_amdgcn_mfma_f32_32x32x16_f16(w1f[jt], bq1.v, kZero, 0, 0, 0);
        FragU p0lo, p0hi, p1lo, p1hi;
        #pragma unroll
        for (int r = 0; r < 4; ++r) {
            p0lo.h[r] = pkrtz(fmaxf(h0[2*r],   0.f), fmaxf(h0[2*r+1],   0.f));
            p0hi.h[r] = pkrtz(fmaxf(h0[8+2*r], 0.f), fmaxf(h0[8+2*r+1], 0.f));
            p1lo.h[r] = pkrtz(fmaxf(h1[2*r],   0.f), fmaxf(h1[2*r+1],   0.f));
            p1hi.h[r] = pkrtz(fmaxf(h1[8+2*r], 0.f), fmaxf(h1[8+2*r+1], 0.f));
        }
        accA = __builtin_amdgcn_mfma_f32_32x32x16_f16(w2f[2*jt],     p0lo.v, accA, 0, 0, 0);
        accA = __builtin_amdgcn_mfma_f32_32x32x16_f16(w2f[2*jt + 1], p0hi.v, accA, 0, 0, 0);
        accB = __builtin_amdgcn_mfma_f32_32x32x16_f16(w2f[2*jt],     p1lo.v, accB, 0, 0, 0);
        accB = __builtin_amdgcn_mfma_f32_32x32x16_f16(w2f[2*jt + 1], p1hi.v, accB, 0, 0, 0);
    }

    // ---- epilogue: thread's sample = its lane; q5 picks group ----
    float a0 = q5 ? accB[0] : accA[0];
    float a1 = q5 ? accB[1] : accA[1];
    float a2 = q5 ? accB[2] : accA[2];

    float o0 = fmaxf(a0, 0.0f) + log1pf(expf(-fabsf(a0)));
    float o1 = fmaxf(a1, 0.0f) + log1pf(expf(-fabsf(a1)));
    float o2 = fmaxf(a2, 0.0f) + log1pf(expf(-fabsf(a2)));

    out[3 * i + 0] = o0;
    out[3 * i + 1] = o1;
    out[3 * i + 2] = o2;
}

extern "C" void kernel_launch(void* const* d_in, const int* in_sizes, int n_in,
                              void* d_out, int out_size, void* d_ws, size_t ws_size,
                              hipStream_t stream) {
    const float* viewdirs = (const float*)d_in[0];
    // d_in[1] = roughness: unused by the reference
    const float* bg_mat   = (const float*)d_in[2];
    const float* W1       = (const float*)d_in[3];
    const float* W2       = (const float*)d_in[4];
    float* out            = (float*)d_out;

    const size_t tex_bytes = (size_t)HW * RANK * sizeof(__half);   // 16 MB
    const int nblocks = NB / TPB;   // 4096

    if (ws_size >= tex_bytes) {
        __half* tex = (__half*)d_ws;
        transpose_f16_kernel<<<dim3(HW / 256), dim3(256), 0, stream>>>(bg_mat, tex);
        bg_render_mfma<0><<<dim3(nblocks), dim3(TPB), 0, stream>>>(
            viewdirs, (const void*)tex, W1, W2, out);
    } else {
        bg_render_mfma<1><<<dim3(nblocks), dim3(TPB), 0, stream>>>(
            viewdirs, (const void*)bg_mat, W1, W2, out);
    }
}

// Round 8
// 71.255 us; speedup vs baseline: 1.3319x; 1.3319x over previous
//
#include <hip/hip_runtime.h>
#include <hip/hip_fp16.h>
#include <math.h>

#define NB    (1 << 20)
#define HH    512
#define WW    1024
#define RANK  16
#define FC    128
#define HW    (HH * WW)
#define TPB   256

typedef float        f32x16 __attribute__((ext_vector_type(16)));
typedef _Float16     f16x8  __attribute__((ext_vector_type(8)));
typedef _Float16     h2     __attribute__((ext_vector_type(2)));
typedef unsigned int uint2v __attribute__((ext_vector_type(2)));

// cvt_pkrtz returns __fp16x2; bit-identical re-type to our h2 (_Float16x2)
__device__ __forceinline__ h2 pkrtz(float a, float b) {
    return __builtin_bit_cast(h2, __builtin_amdgcn_cvt_pkrtz(a, b));
}

// ---------------------------------------------------------------------------
// Pre-pass 1: planar bg_mat [16][H][W] fp32 -> interleaved f16 tex [H*W][16]
// ---------------------------------------------------------------------------
__global__ __launch_bounds__(256) void transpose_f16_kernel(
    const float* __restrict__ bg, __half* __restrict__ tex)
{
    const int t = blockIdx.x * 256 + threadIdx.x;
    union { unsigned short s[16]; uint4 q[2]; } pk;
    #pragma unroll
    for (int c = 0; c < RANK; ++c) {
        __half h = __float2half_rn(bg[c * HW + t]);
        pk.s[c] = *reinterpret_cast<unsigned short*>(&h);
    }
    uint4* dst = (uint4*)(tex + (size_t)t * 16);
    dst[0] = pk.q[0];
    dst[1] = pk.q[1];
}

// ---------------------------------------------------------------------------
// Pre-pass 2: per-lane MFMA weight-fragment table (depends only on lane id).
// Layout: table[frag][lane] with frag 0-3 = w1f, 4-11 = w2f. 12KB total.
// One wave computes it once; every main-kernel wave loads it coalesced
// (12x dwordx4, L1-resident).
// ---------------------------------------------------------------------------
__global__ __launch_bounds__(64) void build_frag_table(
    const float* __restrict__ W1,      // [16][128] row-major
    const float* __restrict__ W2,      // [128][3] row-major
    f16x8* __restrict__ table)         // [12][64]
{
    const int lane = threadIdx.x;      // 0..63
    const int l31  = lane & 31;
    const int q5   = (lane >> 5) & 1;

    // GEMM1 A-fragments: A[row=j_local][k] = W1[k][32*jt + j_local]
    #pragma unroll
    for (int jt = 0; jt < 4; ++jt) {
        f16x8 v;
        #pragma unroll
        for (int ii = 0; ii < 8; ++ii)
            v[ii] = (_Float16)W1[(8 * q5 + ii) * FC + 32 * jt + l31];
        table[jt * 64 + lane] = v;
    }
    // GEMM2 A-fragments, K-permuted: neuron n = 16*kt+8*(ii>>2)+4*q5+(ii&3);
    // rows 0-2 = W2 cols, rows 4-6 duplicate them for the upper lane-half.
    const bool ok = ((l31 & 3) < 3) && (l31 < 8);
    const int  c3 = l31 & 3;
    #pragma unroll
    for (int kt = 0; kt < 8; ++kt) {
        f16x8 v;
        #pragma unroll
        for (int ii = 0; ii < 8; ++ii) {
            const int n = 16 * kt + 8 * (ii >> 2) + 4 * q5 + (ii & 3);
            v[ii] = ok ? (_Float16)W2[3 * n + c3] : (_Float16)0.0f;
        }
        table[(4 + kt) * 64 + lane] = v;
    }
}

// ---------------------------------------------------------------------------
// Fused render, all-f16 datapath, 1 sample/thread, barrier-free:
// gather(f16 tex) -> pk_fma blend (result IS the MFMA B-fragment)
// -> permlane32_swap wave transpose -> GEMM1 16->128 (f16 MFMA) -> relu +
// cvt_pkrtz -> GEMM2 128->3 (f16 MFMA, K-permuted so GEMM1 C-layout ==
// GEMM2 B-layout). Weight fragments come from the precomputed table.
// MODE 0: f16 tex + table; MODE 1: planar f32 + inline weights (fallback).
// ---------------------------------------------------------------------------
template <int MODE>
__global__ __launch_bounds__(TPB, 3) void bg_render_mfma(
    const float* __restrict__ viewdirs,
    const void*  __restrict__ srcv,
    const f16x8* __restrict__ ftab,    // MODE 0 only
    const float* __restrict__ W1,
    const float* __restrict__ W2,
    float* __restrict__ out)
{
    const int tid  = threadIdx.x;
    const int lane = tid & 63;
    const int l31  = tid & 31;
    const int q5   = (tid >> 5) & 1;

    const f32x16 kZero = {0.f,0.f,0.f,0.f,0.f,0.f,0.f,0.f,
                          0.f,0.f,0.f,0.f,0.f,0.f,0.f,0.f};

    // ---- weight fragments ----
    f16x8 w1f[4], w2f[8];
    if (MODE == 0) {
        #pragma unroll
        for (int f = 0; f < 4; ++f) w1f[f] = ftab[f * 64 + lane];
        #pragma unroll
        for (int f = 0; f < 8; ++f) w2f[f] = ftab[(4 + f) * 64 + lane];
    } else {
        #pragma unroll
        for (int jt = 0; jt < 4; ++jt) {
            f16x8 v;
            #pragma unroll
            for (int ii = 0; ii < 8; ++ii)
                v[ii] = (_Float16)W1[(8 * q5 + ii) * FC + 32 * jt + l31];
            w1f[jt] = v;
        }
        const bool ok = ((l31 & 3) < 3) && (l31 < 8);
        const int  c3 = l31 & 3;
        #pragma unroll
        for (int kt = 0; kt < 8; ++kt) {
            f16x8 v;
            #pragma unroll
            for (int ii = 0; ii < 8; ++ii) {
                const int n = 16 * kt + 8 * (ii >> 2) + 4 * q5 + (ii & 3);
                v[ii] = ok ? (_Float16)W2[3 * n + c3] : (_Float16)0.0f;
            }
            w2f[kt] = v;
        }
    }

    const int i = blockIdx.x * TPB + tid;   // this thread's sample

    // ---- equirect unwrap + bilinear setup (identical math to reference) ----
    const float dx = viewdirs[3 * i + 0];
    const float dy = viewdirs[3 * i + 1];
    const float dz = viewdirs[3 * i + 2];
    const float INV_PI = 0.31830988618379067154f;
    float phi   = atan2f(dy, dx);
    float theta = acosf(fminf(fmaxf(dz, -1.0f), 1.0f));
    float gx = phi * INV_PI;
    float gy = theta * (2.0f * INV_PI) - 1.0f;

    float ix = (gx + 1.0f) * (0.5f * (float)WW) - 0.5f;
    float iy = (gy + 1.0f) * (0.5f * (float)HH) - 0.5f;
    float x0f = floorf(ix), y0f = floorf(iy);
    float wx1 = ix - x0f, wx0 = 1.0f - wx1;
    float wy1 = iy - y0f, wy0 = 1.0f - wy1;
    int x0 = (int)x0f, y0 = (int)y0f;
    int x1 = x0 + 1,   y1 = y0 + 1;

    float w00 = wx0 * wy0, w10 = wx1 * wy0, w01 = wx0 * wy1, w11 = wx1 * wy1;
    bool vx0 = (x0 >= 0) & (x0 <= WW - 1);
    bool vx1 = (x1 >= 0) & (x1 <= WW - 1);
    bool vy0 = (y0 >= 0) & (y0 <= HH - 1);
    bool vy1 = (y1 >= 0) & (y1 <= HH - 1);
    if (!(vx0 & vy0)) w00 = 0.0f;
    if (!(vx1 & vy0)) w10 = 0.0f;
    if (!(vx0 & vy1)) w01 = 0.0f;
    if (!(vx1 & vy1)) w11 = 0.0f;

    int cx0 = min(max(x0, 0), WW - 1), cx1 = min(max(x1, 0), WW - 1);
    int cy0 = min(max(y0, 0), HH - 1), cy1 = min(max(y1, 0), HH - 1);
    int b00 = cy0 * WW + cx0, b10 = cy0 * WW + cx1;
    int b01 = cy1 * WW + cx0, b11 = cy1 * WW + cx1;

    // ---- gather + blend: e[8] (h2) = this sample's 16-ch emb in f16 ----
    h2 e[8];
    if (MODE == 0) {
        const __half* tex = (const __half*)srcv;
        union Tap { uint4 q[2]; h2 h[8]; } t00, t10, t01, t11;
        const uint4* p;
        p = (const uint4*)(tex + (size_t)b00 * 16); t00.q[0] = p[0]; t00.q[1] = p[1];
        p = (const uint4*)(tex + (size_t)b10 * 16); t10.q[0] = p[0]; t10.q[1] = p[1];
        p = (const uint4*)(tex + (size_t)b01 * 16); t01.q[0] = p[0]; t01.q[1] = p[1];
        p = (const uint4*)(tex + (size_t)b11 * 16); t11.q[0] = p[0]; t11.q[1] = p[1];

        h2 W00, W10, W01, W11;
        W00[0] = W00[1] = (_Float16)w00;
        W10[0] = W10[1] = (_Float16)w10;
        W01[0] = W01[1] = (_Float16)w01;
        W11[0] = W11[1] = (_Float16)w11;
        #pragma unroll
        for (int d = 0; d < 8; ++d)
            e[d] = t00.h[d] * W00 + t10.h[d] * W10 + t01.h[d] * W01 + t11.h[d] * W11;
    } else {
        const float* src = (const float*)srcv;
        float ef[RANK];
        #pragma unroll
        for (int ch = 0; ch < RANK; ++ch) {
            const float* img = src + ch * HW;
            ef[ch] = img[b00] * w00 + img[b10] * w10
                   + img[b01] * w01 + img[b11] * w11;
        }
        #pragma unroll
        for (int d = 0; d < 8; ++d)
            e[d] = pkrtz(ef[2 * d], ef[2 * d + 1]);
    }

    // ---- wave transpose: 4 permlane32_swap build BOTH groups' B-frags ----
    union FragU { f16x8 v; h2 h[4]; unsigned int u[4]; };
    FragU bq0, bq1;
    #pragma unroll
    for (int d = 0; d < 4; ++d) {
        unsigned int lo = __builtin_bit_cast(unsigned int, e[d]);
        unsigned int hi = __builtin_bit_cast(unsigned int, e[d + 4]);
        uint2v r = __builtin_amdgcn_permlane32_swap(lo, hi, false, false);
        bq0.u[d] = r.x;
        bq1.u[d] = r.y;
    }

    // ---- MFMA pipeline: 4 jt x (2 GEMM1 + 4 GEMM2), all f16 ----
    f32x16 accA = kZero, accB = kZero;
    #pragma unroll
    for (int jt = 0; jt < 4; ++jt) {
        f32x16 h0 = __builtin_amdgcn_mfma_f32_32x32x16_f16(w1f[jt], bq0.v, kZero, 0, 0, 0);
        FragU p0lo, p0hi;
        #pragma unroll
        for (int r = 0; r < 4; ++r) {
            p0lo.h[r] = pkrtz(fmaxf(h0[2*r],   0.f), fmaxf(h0[2*r+1],   0.f));
            p0hi.h[r] = pkrtz(fmaxf(h0[8+2*r], 0.f), fmaxf(h0[8+2*r+1], 0.f));
        }
        accA = __builtin_amdgcn_mfma_f32_32x32x16_f16(w2f[2*jt],     p0lo.v, accA, 0, 0, 0);
        accA = __builtin_amdgcn_mfma_f32_32x32x16_f16(w2f[2*jt + 1], p0hi.v, accA, 0, 0, 0);

        f32x16 h1 = __builtin_amdgcn_mfma_f32_32x32x16_f16(w1f[jt], bq1.v, kZero, 0, 0, 0);
        FragU p1lo, p1hi;
        #pragma unroll
        for (int r = 0; r < 4; ++r) {
            p1lo.h[r] = pkrtz(fmaxf(h1[2*r],   0.f), fmaxf(h1[2*r+1],   0.f));
            p1hi.h[r] = pkrtz(fmaxf(h1[8+2*r], 0.f), fmaxf(h1[8+2*r+1], 0.f));
        }
        accB = __builtin_amdgcn_mfma_f32_32x32x16_f16(w2f[2*jt],     p1lo.v, accB, 0, 0, 0);
        accB = __builtin_amdgcn_mfma_f32_32x32x16_f16(w2f[2*jt + 1], p1hi.v, accB, 0, 0, 0);
    }

    // ---- epilogue: thread's sample = its lane; q5 picks group ----
    float a0 = q5 ? accB[0] : accA[0];
    float a1 = q5 ? accB[1] : accA[1];
    float a2 = q5 ? accB[2] : accA[2];

    float o0 = fmaxf(a0, 0.0f) + log1pf(expf(-fabsf(a0)));
    float o1 = fmaxf(a1, 0.0f) + log1pf(expf(-fabsf(a1)));
    float o2 = fmaxf(a2, 0.0f) + log1pf(expf(-fabsf(a2)));

    out[3 * i + 0] = o0;
    out[3 * i + 1] = o1;
    out[3 * i + 2] = o2;
}

extern "C" void kernel_launch(void* const* d_in, const int* in_sizes, int n_in,
                              void* d_out, int out_size, void* d_ws, size_t ws_size,
                              hipStream_t stream) {
    const float* viewdirs = (const float*)d_in[0];
    // d_in[1] = roughness: unused by the reference
    const float* bg_mat   = (const float*)d_in[2];
    const float* W1       = (const float*)d_in[3];
    const float* W2       = (const float*)d_in[4];
    float* out            = (float*)d_out;

    const size_t tex_bytes = (size_t)HW * RANK * sizeof(__half);   // 16 MB
    const size_t tab_bytes = (size_t)12 * 64 * sizeof(f16x8);      // 12 KB
    const int nblocks = NB / TPB;   // 4096

    if (ws_size >= tex_bytes + tab_bytes) {
        __half* tex  = (__half*)d_ws;
        f16x8*  ftab = (f16x8*)((char*)d_ws + tex_bytes);
        transpose_f16_kernel<<<dim3(HW / 256), dim3(256), 0, stream>>>(bg_mat, tex);
        build_frag_table<<<dim3(1), dim3(64), 0, stream>>>(W1, W2, ftab);
        bg_render_mfma<0><<<dim3(nblocks), dim3(TPB), 0, stream>>>(
            viewdirs, (const void*)tex, ftab, W1, W2, out);
    } else {
        bg_render_mfma<1><<<dim3(nblocks), dim3(TPB), 0, stream>>>(
            viewdirs, (const void*)bg_mat, nullptr, W1, W2, out);
    }
}

// Round 10
// 63.659 us; speedup vs baseline: 1.4908x; 1.1193x over previous
//
#include <hip/hip_runtime.h>
#include <hip/hip_fp16.h>
#include <math.h>

#define NB    (1 << 20)
#define HH    512
#define WW    1024
#define RANK  16
#define FC    128
#define HW    (HH * WW)
#define TPB   256

typedef float        f32x16 __attribute__((ext_vector_type(16)));
typedef _Float16     f16x8  __attribute__((ext_vector_type(8)));
typedef _Float16     h2     __attribute__((ext_vector_type(2)));
typedef unsigned int uint2v __attribute__((ext_vector_type(2)));

// cvt_pkrtz returns __fp16x2; bit-identical re-type to our h2 (_Float16x2)
__device__ __forceinline__ h2 pkrtz(float a, float b) {
    return __builtin_bit_cast(h2, __builtin_amdgcn_cvt_pkrtz(a, b));
}
// packed f16 relu (elementwise select -> v_pk_max_f16 / 2x v_max_f16)
__device__ __forceinline__ h2 relu2(h2 a) {
    h2 r;
    r[0] = (a[0] > (_Float16)0.0f) ? a[0] : (_Float16)0.0f;
    r[1] = (a[1] > (_Float16)0.0f) ? a[1] : (_Float16)0.0f;
    return r;
}

// Cephes-style atan2, max err ~1e-7 rad (-> 1.6e-5 px here)
__device__ __forceinline__ float fast_atan2f(float y, float x) {
    float ax = fabsf(x), ay = fabsf(y);
    float mx = fmaxf(ax, ay), mn = fminf(ax, ay);
    float z  = __fdividef(mn, mx);
    if (mx == 0.0f) z = 0.0f;                    // atan2(0,0) = 0
    bool  red = z > 0.41421356f;                 // tan(pi/8) reduction
    float zr  = red ? __fdividef(z - 1.0f, z + 1.0f) : z;
    float t2  = zr * zr;
    float p   = (((0.0805374449f * t2 - 0.138776856f) * t2
                 + 0.199777106f) * t2 - 0.333329491f) * t2 * zr + zr;
    if (red)      p += 0.78539816339f;
    if (ay > ax)  p  = 1.57079632679f - p;
    if (x < 0.0f) p  = 3.14159265359f - p;
    return copysignf(p, y);
}
// A&S 4.4.46 7-term acos, max err ~1e-7 (f32 rounding limited)
__device__ __forceinline__ float fast_acosf(float x) {
    float xa = fabsf(x);
    float p = -0.0012624911f;
    p = p * xa + 0.0066700901f;
    p = p * xa - 0.0170881256f;
    p = p * xa + 0.0308918810f;
    p = p * xa - 0.0501743046f;
    p = p * xa + 0.0889789874f;
    p = p * xa - 0.2145988016f;
    p = p * xa + 1.5707963050f;
    float r = sqrtf(1.0f - xa) * p;
    return x >= 0.0f ? r : 3.14159265359f - r;
}
// softplus via hw exp/log; abs err < 3e-4 (<< 0.017 threshold)
__device__ __forceinline__ float softplusf(float a) {
    return fmaxf(a, 0.0f) + __logf(1.0f + __expf(-fabsf(a)));
}

// ---------------------------------------------------------------------------
// Merged pre-pass: (a) planar bg_mat [16][H][W] fp32 -> interleaved f16 tex
// [H*W][16], 4 texels/thread (float4 reads, 128B contiguous writes);
// (b) block 0 lanes 0-63 also build the 12KB per-lane MFMA fragment table.
// ---------------------------------------------------------------------------
__global__ __launch_bounds__(256) void prep_kernel(
    const float* __restrict__ bg,
    const float* __restrict__ W1,      // [16][128] row-major
    const float* __restrict__ W2,      // [128][3] row-major
    __half* __restrict__ tex,
    f16x8* __restrict__ table)         // [12][64]
{
    const int base = (blockIdx.x * 256 + threadIdx.x) * 4;   // 4 texels
    float4 v[RANK];
    #pragma unroll
    for (int c = 0; c < RANK; ++c)
        v[c] = *(const float4*)(bg + (size_t)c * HW + base);

    const float* vf = (const float*)v;   // v[c][j] == vf[4*c + j]
    #pragma unroll
    for (int j = 0; j < 4; ++j) {
        union { h2 h[8]; uint4 q[2]; } o;
        #pragma unroll
        for (int cc = 0; cc < 8; ++cc)
            o.h[cc] = pkrtz(vf[4 * (2 * cc) + j], vf[4 * (2 * cc + 1) + j]);
        uint4* dst = (uint4*)(tex + (size_t)(base + j) * 16);
        dst[0] = o.q[0];
        dst[1] = o.q[1];
    }

    if (blockIdx.x == 0 && threadIdx.x < 64) {
        const int lane = threadIdx.x;
        const int l31  = lane & 31;
        const int q5   = (lane >> 5) & 1;
        // GEMM1 A-fragments: A[row=j_local][k] = W1[k][32*jt + j_local]
        #pragma unroll
        for (int jt = 0; jt < 4; ++jt) {
            f16x8 w;
            #pragma unroll
            for (int ii = 0; ii < 8; ++ii)
                w[ii] = (_Float16)W1[(8 * q5 + ii) * FC + 32 * jt + l31];
            table[jt * 64 + lane] = w;
        }
        // GEMM2 A-fragments, K-permuted: n = 16*kt+8*(ii>>2)+4*q5+(ii&3);
        // rows 0-2 = W2 cols, rows 4-6 duplicate for the upper lane-half.
        const bool ok = ((l31 & 3) < 3) && (l31 < 8);
        const int  c3 = l31 & 3;
        #pragma unroll
        for (int kt = 0; kt < 8; ++kt) {
            f16x8 w;
            #pragma unroll
            for (int ii = 0; ii < 8; ++ii) {
                const int n = 16 * kt + 8 * (ii >> 2) + 4 * q5 + (ii & 3);
                w[ii] = ok ? (_Float16)W2[3 * n + c3] : (_Float16)0.0f;
            }
            table[(4 + kt) * 64 + lane] = w;
        }
    }
}

// ---------------------------------------------------------------------------
// Fused render, all-f16 datapath, 1 sample/thread, barrier-free:
// gather(f16 tex) -> pk_fma blend (result IS the MFMA B-fragment)
// -> permlane32_swap wave transpose -> GEMM1 16->128 (f16 MFMA) -> relu +
// cvt_pkrtz -> GEMM2 128->3 (f16 MFMA, K-permuted so GEMM1 C-layout ==
// GEMM2 B-layout). Sequential per-group MLP = one live f32x16 acc.
// MODE 0: f16 tex + frag table; MODE 1: planar f32 + inline weights.
// ---------------------------------------------------------------------------
template <int MODE>
__global__ __launch_bounds__(TPB, 4) void bg_render_mfma(
    const float* __restrict__ viewdirs,
    const void*  __restrict__ srcv,
    const f16x8* __restrict__ ftab,    // MODE 0 only
    const float* __restrict__ W1,
    const float* __restrict__ W2,
    float* __restrict__ out)
{
    const int tid  = threadIdx.x;
    const int lane = tid & 63;
    const int l31  = tid & 31;
    const int q5   = (tid >> 5) & 1;

    const f32x16 kZero = {0.f,0.f,0.f,0.f,0.f,0.f,0.f,0.f,
                          0.f,0.f,0.f,0.f,0.f,0.f,0.f,0.f};

    const int i = blockIdx.x * TPB + tid;   // this thread's sample

    // ---- equirect unwrap + bilinear setup (matches reference math) ----
    const float dx = viewdirs[3 * i + 0];
    const float dy = viewdirs[3 * i + 1];
    const float dz = viewdirs[3 * i + 2];
    const float INV_PI = 0.31830988618379067154f;
    float phi   = fast_atan2f(dy, dx);
    float theta = fast_acosf(fminf(fmaxf(dz, -1.0f), 1.0f));
    float gx = phi * INV_PI;
    float gy = theta * (2.0f * INV_PI) - 1.0f;

    float ix = (gx + 1.0f) * (0.5f * (float)WW) - 0.5f;
    float iy = (gy + 1.0f) * (0.5f * (float)HH) - 0.5f;
    float x0f = floorf(ix), y0f = floorf(iy);
    float wx1 = ix - x0f, wx0 = 1.0f - wx1;
    float wy1 = iy - y0f, wy0 = 1.0f - wy1;
    int x0 = (int)x0f, y0 = (int)y0f;
    int x1 = x0 + 1,   y1 = y0 + 1;

    float w00 = wx0 * wy0, w10 = wx1 * wy0, w01 = wx0 * wy1, w11 = wx1 * wy1;
    bool vx0 = (x0 >= 0) & (x0 <= WW - 1);
    bool vx1 = (x1 >= 0) & (x1 <= WW - 1);
    bool vy0 = (y0 >= 0) & (y0 <= HH - 1);
    bool vy1 = (y1 >= 0) & (y1 <= HH - 1);
    if (!(vx0 & vy0)) w00 = 0.0f;
    if (!(vx1 & vy0)) w10 = 0.0f;
    if (!(vx0 & vy1)) w01 = 0.0f;
    if (!(vx1 & vy1)) w11 = 0.0f;

    int cx0 = min(max(x0, 0), WW - 1), cx1 = min(max(x1, 0), WW - 1);
    int cy0 = min(max(y0, 0), HH - 1), cy1 = min(max(y1, 0), HH - 1);
    int b00 = cy0 * WW + cx0, b10 = cy0 * WW + cx1;
    int b01 = cy1 * WW + cx0, b11 = cy1 * WW + cx1;

    // ---- issue tap loads FIRST, then weight-fragment loads (L1-resident) ----
    h2 e[8];
    f16x8 w1f[4], w2f[8];
    if (MODE == 0) {
        const __half* tex = (const __half*)srcv;
        union Tap { uint4 q[2]; h2 h[8]; } t00, t10, t01, t11;
        const uint4* p;
        p = (const uint4*)(tex + (size_t)b00 * 16); t00.q[0] = p[0]; t00.q[1] = p[1];
        p = (const uint4*)(tex + (size_t)b10 * 16); t10.q[0] = p[0]; t10.q[1] = p[1];
        p = (const uint4*)(tex + (size_t)b01 * 16); t01.q[0] = p[0]; t01.q[1] = p[1];
        p = (const uint4*)(tex + (size_t)b11 * 16); t11.q[0] = p[0]; t11.q[1] = p[1];

        #pragma unroll
        for (int f = 0; f < 4; ++f) w1f[f] = ftab[f * 64 + lane];
        #pragma unroll
        for (int f = 0; f < 8; ++f) w2f[f] = ftab[(4 + f) * 64 + lane];

        h2 W00, W10, W01, W11;
        W00[0] = W00[1] = (_Float16)w00;
        W10[0] = W10[1] = (_Float16)w10;
        W01[0] = W01[1] = (_Float16)w01;
        W11[0] = W11[1] = (_Float16)w11;
        #pragma unroll
        for (int d = 0; d < 8; ++d)
            e[d] = t00.h[d] * W00 + t10.h[d] * W10 + t01.h[d] * W01 + t11.h[d] * W11;
    } else {
        const float* src = (const float*)srcv;
        float ef[RANK];
        #pragma unroll
        for (int ch = 0; ch < RANK; ++ch) {
            const float* img = src + ch * HW;
            ef[ch] = img[b00] * w00 + img[b10] * w10
                   + img[b01] * w01 + img[b11] * w11;
        }
        #pragma unroll
        for (int d = 0; d < 8; ++d)
            e[d] = pkrtz(ef[2 * d], ef[2 * d + 1]);

        #pragma unroll
        for (int jt = 0; jt < 4; ++jt) {
            f16x8 v;
            #pragma unroll
            for (int ii = 0; ii < 8; ++ii)
                v[ii] = (_Float16)W1[(8 * q5 + ii) * FC + 32 * jt + l31];
            w1f[jt] = v;
        }
        const bool ok = ((l31 & 3) < 3) && (l31 < 8);
        const int  c3 = l31 & 3;
        #pragma unroll
        for (int kt = 0; kt < 8; ++kt) {
            f16x8 v;
            #pragma unroll
            for (int ii = 0; ii < 8; ++ii) {
                const int n = 16 * kt + 8 * (ii >> 2) + 4 * q5 + (ii & 3);
                v[ii] = ok ? (_Float16)W2[3 * n + c3] : (_Float16)0.0f;
            }
            w2f[kt] = v;
        }
    }

    // ---- wave transpose: 4 permlane32_swap build BOTH groups' B-frags ----
    union FragU { f16x8 v; h2 h[4]; unsigned int u[4]; };
    FragU bq0, bq1;
    #pragma unroll
    for (int d = 0; d < 4; ++d) {
        unsigned int lo = __builtin_bit_cast(unsigned int, e[d]);
        unsigned int hi = __builtin_bit_cast(unsigned int, e[d + 4]);
        uint2v r = __builtin_amdgcn_permlane32_swap(lo, hi, false, false);
        bq0.u[d] = r.x;
        bq1.u[d] = r.y;
    }

    // ---- MFMA pipeline, sequential groups (one live f32x16 acc) ----
    float ag[2][3];
    #pragma unroll
    for (int g = 0; g < 2; ++g) {
        const f16x8 bq = (g == 0) ? bq0.v : bq1.v;
        f32x16 acc = kZero;
        #pragma unroll
        for (int jt = 0; jt < 4; ++jt) {
            f32x16 h = __builtin_amdgcn_mfma_f32_32x32x16_f16(w1f[jt], bq, kZero, 0, 0, 0);
            FragU plo, phi_;
            #pragma unroll
            for (int r = 0; r < 4; ++r) {
                plo.h[r]  = relu2(pkrtz(h[2*r],     h[2*r + 1]));
                phi_.h[r] = relu2(pkrtz(h[8 + 2*r], h[8 + 2*r + 1]));
            }
            acc = __builtin_amdgcn_mfma_f32_32x32x16_f16(w2f[2*jt],     plo.v,  acc, 0, 0, 0);
            acc = __builtin_amdgcn_mfma_f32_32x32x16_f16(w2f[2*jt + 1], phi_.v, acc, 0, 0, 0);
        }
        ag[g][0] = acc[0]; ag[g][1] = acc[1]; ag[g][2] = acc[2];
    }

    // ---- epilogue: thread's sample = its lane; q5 picks group ----
    float a0 = q5 ? ag[1][0] : ag[0][0];
    float a1 = q5 ? ag[1][1] : ag[0][1];
    float a2 = q5 ? ag[1][2] : ag[0][2];

    out[3 * i + 0] = softplusf(a0);
    out[3 * i + 1] = softplusf(a1);
    out[3 * i + 2] = softplusf(a2);
}

extern "C" void kernel_launch(void* const* d_in, const int* in_sizes, int n_in,
                              void* d_out, int out_size, void* d_ws, size_t ws_size,
                              hipStream_t stream) {
    const float* viewdirs = (const float*)d_in[0];
    // d_in[1] = roughness: unused by the reference
    const float* bg_mat   = (const float*)d_in[2];
    const float* W1       = (const float*)d_in[3];
    const float* W2       = (const float*)d_in[4];
    float* out            = (float*)d_out;

    const size_t tex_bytes = (size_t)HW * RANK * sizeof(__half);   // 16 MB
    const size_t tab_bytes = (size_t)12 * 64 * sizeof(f16x8);      // 12 KB
    const int nblocks = NB / TPB;   // 4096

    if (ws_size >= tex_bytes + tab_bytes) {
        __half* tex  = (__half*)d_ws;
        f16x8*  ftab = (f16x8*)((char*)d_ws + tex_bytes);
        prep_kernel<<<dim3(HW / 1024), dim3(256), 0, stream>>>(bg_mat, W1, W2, tex, ftab);
        bg_render_mfma<0><<<dim3(nblocks), dim3(TPB), 0, stream>>>(
            viewdirs, (const void*)tex, ftab, W1, W2, out);
    } else {
        bg_render_mfma<1><<<dim3(nblocks), dim3(TPB), 0, stream>>>(
            viewdirs, (const void*)bg_mat, nullptr, W1, W2, out);
    }
}